// Round 9
// baseline (376.974 us; speedup 1.0000x reference)
//
#include <hip/hip_runtime.h>
#include <math.h>

// Problem constants (fixed by the reference)
#define SPATIAL (64*64*64)   // 262144 elements per (b, channel)
#define SPATIAL4 (SPATIAL/4) // 65536 float4 per channel
#define NCH 64
#define BN_EPS 1e-5f

// clang-native 4-float vector for nontemporal builtins
typedef float v4f __attribute__((ext_vector_type(4)));

// -------- Kernel 1: persistent channel-strided partial sums ----------------
// 1024 blocks x 256 threads = EXACTLY 4 blocks/CU resident (no ramp/drain;
// r8's one-shot 2048 blocks showed 32.8% occupancy from ramp artifacts).
// Each block: batch=blk>>9, chunk-group cg=blk&511, handles chunks cg and
// cg+512. 32 per-channel accumulators live in registers across both chunks;
// the 64-lane butterfly is paid ONCE at the end (r8 paid it per chunk).
// g loads nontemporal (g can't be L3-resident; don't evict x).
__global__ __launch_bounds__(256) void mean_kernel(const float* __restrict__ g,
                                                   const float* __restrict__ x,
                                                   float* __restrict__ wpart) {
    int t     = threadIdx.x;
    int lane  = t & 63;
    int grp   = t >> 6;                 // 0..3 (== wave id)
    int blk   = blockIdx.x;             // 0..1023
    int batch = blk >> 9;               // 512 blocks per batch
    int cg    = blk & 511;              // handles chunks cg, cg+512
    size_t chBase = (size_t)batch * NCH * SPATIAL4
                  + (size_t)(grp * 16) * SPATIAL4;

    float ga0=0,ga1=0,ga2=0,ga3=0,ga4=0,ga5=0,ga6=0,ga7=0,
          ga8=0,ga9=0,ga10=0,ga11=0,ga12=0,ga13=0,ga14=0,ga15=0;
    float xa0=0,xa1=0,xa2=0,xa3=0,xa4=0,xa5=0,xa6=0,xa7=0,
          xa8=0,xa9=0,xa10=0,xa11=0,xa12=0,xa13=0,xa14=0,xa15=0;

#define LDG(n) { v4f v = __builtin_nontemporal_load(gp + (size_t)(n) * SPATIAL4); \
                 ga##n += (v.x + v.y) + (v.z + v.w); }
#define LDX(n) { v4f v = xp[(size_t)(n) * SPATIAL4]; \
                 xa##n += (v.x + v.y) + (v.z + v.w); }
#define CHUNK(c) { \
    const v4f* gp = (const v4f*)g + chBase + (size_t)((c) * 64 + lane); \
    const v4f* xp = (const v4f*)x + chBase + (size_t)((c) * 64 + lane); \
    LDG(0) LDG(1) LDG(2) LDG(3) LDG(4) LDG(5) LDG(6) LDG(7) \
    LDG(8) LDG(9) LDG(10) LDG(11) LDG(12) LDG(13) LDG(14) LDG(15) \
    LDX(0) LDX(1) LDX(2) LDX(3) LDX(4) LDX(5) LDX(6) LDX(7) \
    LDX(8) LDX(9) LDX(10) LDX(11) LDX(12) LDX(13) LDX(14) LDX(15) }

    CHUNK(cg)
    CHUNK(cg + 512)
#undef LDG
#undef LDX
#undef CHUNK

#define RED(v) { v += __shfl_xor(v, 32, 64); v += __shfl_xor(v, 16, 64); \
                 v += __shfl_xor(v,  8, 64); v += __shfl_xor(v,  4, 64); \
                 v += __shfl_xor(v,  2, 64); v += __shfl_xor(v,  1, 64); }
    RED(ga0) RED(ga1) RED(ga2) RED(ga3) RED(ga4) RED(ga5) RED(ga6) RED(ga7)
    RED(ga8) RED(ga9) RED(ga10) RED(ga11) RED(ga12) RED(ga13) RED(ga14) RED(ga15)
    RED(xa0) RED(xa1) RED(xa2) RED(xa3) RED(xa4) RED(xa5) RED(xa6) RED(xa7)
    RED(xa8) RED(xa9) RED(xa10) RED(xa11) RED(xa12) RED(xa13) RED(xa14) RED(xa15)
#undef RED

    // wpart row layout: [cg][256 features]; feature = batch*64+c for g,
    // 128+batch*64+c for x. batch0/batch1 blocks write disjoint columns.
    if (lane == 0) {
        float* wr = wpart + (size_t)cg * 256 + batch * 64 + grp * 16;
        wr[0]=ga0;  wr[1]=ga1;  wr[2]=ga2;  wr[3]=ga3;
        wr[4]=ga4;  wr[5]=ga5;  wr[6]=ga6;  wr[7]=ga7;
        wr[8]=ga8;  wr[9]=ga9;  wr[10]=ga10; wr[11]=ga11;
        wr[12]=ga12; wr[13]=ga13; wr[14]=ga14; wr[15]=ga15;
        float* wr2 = wr + 128;
        wr2[0]=xa0;  wr2[1]=xa1;  wr2[2]=xa2;  wr2[3]=xa3;
        wr2[4]=xa4;  wr2[5]=xa5;  wr2[6]=xa6;  wr2[7]=xa7;
        wr2[8]=xa8;  wr2[9]=xa9;  wr2[10]=xa10; wr2[11]=xa11;
        wr2[12]=xa12; wr2[13]=xa13; wr2[14]=xa14; wr2[15]=xa15;
    }
}

// -------- Kernel 1b: fold 512 chunk-partials per feature -> pooled ---------
// 256 blocks (one per feature) x 256 threads; reads 512 KB (L2-resident).
__global__ __launch_bounds__(256) void fold_kernel(const float* __restrict__ wpart,
                                                   float* __restrict__ pooled) {
    int f   = blockIdx.x;         // 0..255 feature
    int tid = threadIdx.x;
    float s = wpart[(size_t)tid * 256 + f]
            + wpart[(size_t)(tid + 256) * 256 + f];
    #pragma unroll
    for (int off = 32; off > 0; off >>= 1)
        s += __shfl_down(s, off, 64);
    __shared__ float ws[4];
    if ((tid & 63) == 0) ws[tid >> 6] = s;
    __syncthreads();
    if (tid == 0) {
        float tot = (ws[0] + ws[1]) + (ws[2] + ws[3]);
        int pi;
        if (f < 128) { int b = f >> 6, c = f & 63; pi = b * 128 + c; }
        else         { int b = (f - 128) >> 6, c = f & 63; pi = b * 128 + 64 + c; }
        pooled[pi] = tot * (1.0f / SPATIAL);
    }
}

// -------- Kernel 2: gating MLP -> 128 coefs + bias -------------------------
__global__ __launch_bounds__(64) void mlp_kernel(const float* __restrict__ pooled,
                           const float* __restrict__ w1, const float* __restrict__ b1,
                           const float* __restrict__ w2, const float* __restrict__ b2,
                           const float* __restrict__ psi_w, const float* __restrict__ psi_b,
                           const float* __restrict__ bn_gamma, const float* __restrict__ bn_beta,
                           const float* __restrict__ bn_mean, const float* __restrict__ bn_var,
                           float* __restrict__ coef) {
    __shared__ float p[256];   // pooled, layout [b*128 + feature]
    __shared__ float h[32];    // hidden for this block's batch
    int tid = threadIdx.x;     // 0..63
    int blk = blockIdx.x;      // 0..127
    int b = blk >> 6, gc = blk & 63;

    #pragma unroll
    for (int i = tid; i < 256; i += 64) p[i] = pooled[i];
    __syncthreads();
    if (tid < 32) {
        float acc = b1[tid];
        const float* wr = w1 + tid * 128;
        #pragma unroll 4
        for (int k = 0; k < 128; ++k) acc += p[b * 128 + k] * wr[k];
        h[tid] = fmaxf(acc, 0.f);
    }
    __syncthreads();
    const float4* wr = (const float4*)(w2 + (size_t)(gc * 64 + tid) * 32);
    float z = b2[gc * 64 + tid];
    #pragma unroll
    for (int j = 0; j < 8; ++j) {
        float4 wv = wr[j];
        z += h[4*j] * wv.x + h[4*j+1] * wv.y + h[4*j+2] * wv.z + h[4*j+3] * wv.w;
    }
    float sig = 1.f / (1.f + expf(-z));   // dw[b,gc,l]
    float val = sig * psi_w[tid];
    #pragma unroll
    for (int off = 32; off > 0; off >>= 1)
        val += __shfl_down(val, off, 64);
    float scale = bn_gamma[0] * rsqrtf(bn_var[0] + BN_EPS);
    if (tid == 0) coef[b * 64 + gc] = val * scale;
    if (blk == 0 && tid == 0)
        coef[128] = (psi_b[0] - bn_mean[0]) * scale + bn_beta[0];
}

// -------- Kernel 3: s = sum_g g*c ; out = x * sigmoid(s + bias) ------------
// Change vs r8: the 16 x loads are HOISTED into named registers and issued
// before the LDS/sigmoid phase — they overlap the g fma chain and the
// barriers, so the store phase has zero load waits (r8 serialized 16
// load->store pairs with ~4 in flight). (256,4) gives the ~110-VGPR budget.
__device__ __forceinline__ void fma4(v4f& a, v4f v, float c) {
    a.x += v.x * c; a.y += v.y * c; a.z += v.z * c; a.w += v.w * c;
}

__global__ __launch_bounds__(256, 4) void apply_kernel(const float* __restrict__ g,
                                                       const float* __restrict__ x,
                                                       const float* __restrict__ coef,
                                                       float* __restrict__ out) {
    int t    = threadIdx.x;
    int pos  = t & 63;
    int grp  = t >> 6;                        // 0..3
    int blk  = blockIdx.x;                    // 0..2047
    int batch = blk >> 10;                    // 1024 blocks per batch
    int base4 = (blk & 1023) * 64 + pos;      // float4 index within channel
    size_t chOff = (size_t)batch * NCH * SPATIAL4
                 + (size_t)(grp * 16) * SPATIAL4 + base4;

    const v4f* gp = (const v4f*)g + chOff;
    const v4f* xp = (const v4f*)x + chOff;
    v4f*       op = (v4f*)out + chOff;
    const v4f* cfv = (const v4f*)(coef + batch * NCH + grp * 16);

    v4f acc0 = {0.f,0.f,0.f,0.f}, acc1 = {0.f,0.f,0.f,0.f};
    #pragma unroll
    for (int bq = 0; bq < 4; ++bq) {          // 4 batches of 4 indep g loads
        v4f cv = cfv[bq];
        v4f v0 = __builtin_nontemporal_load(gp + (size_t)(4*bq + 0) * SPATIAL4);
        v4f v1 = __builtin_nontemporal_load(gp + (size_t)(4*bq + 1) * SPATIAL4);
        v4f v2 = __builtin_nontemporal_load(gp + (size_t)(4*bq + 2) * SPATIAL4);
        v4f v3 = __builtin_nontemporal_load(gp + (size_t)(4*bq + 3) * SPATIAL4);
        fma4(acc0, v0, cv.x);
        fma4(acc1, v1, cv.y);
        fma4(acc0, v2, cv.z);
        fma4(acc1, v3, cv.w);
    }
    v4f acc = {acc0.x + acc1.x, acc0.y + acc1.y, acc0.z + acc1.z, acc0.w + acc1.w};

    // hoist all 16 x loads (L3 hits) — overlap LDS/sigmoid phase
    v4f X0,X1,X2,X3,X4,X5,X6,X7,X8,X9,X10,X11,X12,X13,X14,X15;
#define LDX2(n) X##n = xp[(size_t)(n) * SPATIAL4];
    LDX2(0) LDX2(1) LDX2(2) LDX2(3) LDX2(4) LDX2(5) LDX2(6) LDX2(7)
    LDX2(8) LDX2(9) LDX2(10) LDX2(11) LDX2(12) LDX2(13) LDX2(14) LDX2(15)
#undef LDX2

    __shared__ v4f red[4][64];
    if (grp != 0) red[grp][pos] = acc;
    __syncthreads();
    if (grp == 0) {
        v4f r1 = red[1][pos], r2 = red[2][pos], r3 = red[3][pos];
        float d = coef[128];
        v4f s;
        s.x = 1.f / (1.f + expf(-(acc.x + r1.x + r2.x + r3.x + d)));
        s.y = 1.f / (1.f + expf(-(acc.y + r1.y + r2.y + r3.y + d)));
        s.z = 1.f / (1.f + expf(-(acc.z + r1.z + r2.z + r3.z + d)));
        s.w = 1.f / (1.f + expf(-(acc.w + r1.w + r2.w + r3.w + d)));
        red[0][pos] = s;
    }
    __syncthreads();
    v4f s = red[0][pos];

#define ST(n) { v4f ov = {X##n.x * s.x, X##n.y * s.y, X##n.z * s.z, X##n.w * s.w}; \
                __builtin_nontemporal_store(ov, op + (size_t)(n) * SPATIAL4); }
    ST(0) ST(1) ST(2) ST(3) ST(4) ST(5) ST(6) ST(7)
    ST(8) ST(9) ST(10) ST(11) ST(12) ST(13) ST(14) ST(15)
#undef ST
}

extern "C" void kernel_launch(void* const* d_in, const int* in_sizes, int n_in,
                              void* d_out, int out_size, void* d_ws, size_t ws_size,
                              hipStream_t stream) {
    const float* g        = (const float*)d_in[0];
    const float* x        = (const float*)d_in[1];
    const float* w1       = (const float*)d_in[2];
    const float* b1       = (const float*)d_in[3];
    const float* w2       = (const float*)d_in[4];
    const float* b2       = (const float*)d_in[5];
    const float* psi_w    = (const float*)d_in[6];
    const float* psi_b    = (const float*)d_in[7];
    const float* bn_gamma = (const float*)d_in[8];
    const float* bn_beta  = (const float*)d_in[9];
    const float* bn_mean  = (const float*)d_in[10];
    const float* bn_var   = (const float*)d_in[11];
    float* out = (float*)d_out;
    float* ws  = (float*)d_ws;

    float* wpart  = ws;                    // 512*256 floats = 512 KB
    float* pooled = ws + 512 * 256;        // 256 floats
    float* coef   = pooled + 256;          // 129 floats

    mean_kernel<<<1024, 256, 0, stream>>>(g, x, wpart);
    fold_kernel<<<256, 256, 0, stream>>>(wpart, pooled);
    mlp_kernel<<<128, 64, 0, stream>>>(pooled, w1, b1, w2, b2, psi_w, psi_b,
                                       bn_gamma, bn_beta, bn_mean, bn_var, coef);
    apply_kernel<<<2048, 256, 0, stream>>>(g, x, coef, out);
}